// Round 5
// baseline (483.046 us; speedup 1.0000x reference)
//
#include <hip/hip_runtime.h>
#include <hip/hip_fp16.h>

#define N_NODES 200000
#define N_EDGES 6400000
#define F_IN 34
#define F_HID 10
#define F_OUT 4
#define HPAD 12              // 48B rows: bytes 0-19 packed fp16 h*dis (after p5), slot10 = dis fp32
#define BINS 1024
#define NPB 196              // 1024*196 = 200704 >= 200000
#define CHUNK 32768
#define BLK1 ((N_EDGES + CHUNK - 1) / CHUNK)    // 196
#define SCAN_L (BINS * BLK1)                    // 200704
#define NA ((SCAN_L + 255) / 256)               // 784 scanA blocks
#define ACCP 11              // LDS acc padding: gcd(11,32)=1 -> spread banks
#define SORT_CAP 8192        // 32KB LDS sort buffer; bucket avg 6250, sigma~79

// ---------------------------------------------------------------- helpers
__device__ __forceinline__ float2 up2(unsigned u) {
    __half2 h = *reinterpret_cast<const __half2*>(&u);
    return __half22float2(h);
}

// ---------------------------------------------------------------- mode detect
__global__ void detect_mode_kernel(const int* __restrict__ ei, int* __restrict__ mode) {
    int t = threadIdx.x;                 // 64 threads
    int v = ei[2 * t + 1];
    unsigned long long b = __ballot(v != 0);
    if (t == 0) *mode = (b == 0ull) ? 1 : 0;
}

__device__ __forceinline__ int load_idx(const int* ei, long long elem, int mode) {
    return mode ? ei[2 * elem] : ei[elem];
}

// ---------------------------------------------------------------- init: h = x @ W (fp32 rows)
__global__ void init_kernel(const float* __restrict__ x,
                            const float* __restrict__ Wg,
                            float* __restrict__ hpad) {
    __shared__ float Ws[F_IN * F_HID];
    for (int t = threadIdx.x; t < F_IN * F_HID; t += blockDim.x) Ws[t] = Wg[t];
    __syncthreads();

    int i = blockIdx.x * blockDim.x + threadIdx.x;
    if (i >= N_NODES) return;

    float acc[F_HID];
#pragma unroll
    for (int f = 0; f < F_HID; ++f) acc[f] = 0.0f;

    const float* xr = x + (long long)i * F_IN;
#pragma unroll
    for (int k = 0; k < F_IN; ++k) {
        float xv = xr[k];
#pragma unroll
        for (int f = 0; f < F_HID; ++f) acc[f] += xv * Ws[k * F_HID + f];
    }

    float* hr = hpad + (long long)i * HPAD;
#pragma unroll
    for (int f = 0; f < F_HID; ++f) hr[f] = acc[f];
    hr[10] = 0.0f; hr[11] = 0.0f;
}

// ---------------------------------------------------------------- pass 1: bucket counts (LDS hist)
__global__ void p1_count_kernel(const int* __restrict__ ei,
                                const int* __restrict__ mode_p,
                                int* __restrict__ bcnt) {
    __shared__ int hist[BINS];
    const int mode = *mode_p;
    int t = threadIdx.x;
    for (int j = t; j < BINS; j += blockDim.x) hist[j] = 0;
    __syncthreads();

    long long base = (long long)blockIdx.x * CHUNK;
    for (int k = t; k < CHUNK; k += blockDim.x) {
        long long e = base + k;
        if (e >= N_EDGES) break;
        int d = load_idx(ei, (long long)N_EDGES + e, mode);
        if ((unsigned)d < (unsigned)N_NODES) atomicAdd(&hist[d / NPB], 1);
    }
    __syncthreads();
    for (int j = t; j < BINS; j += blockDim.x)
        bcnt[j * BLK1 + blockIdx.x] = hist[j];   // bin-major
}

// ---------------------------------------------------------------- scan A: per-block sums
__global__ void scanA_kernel(const int* __restrict__ src, int* __restrict__ bsum) {
    __shared__ int s[256];
    int t = threadIdx.x;
    int i = blockIdx.x * 256 + t;
    s[t] = (i < SCAN_L) ? src[i] : 0;
    __syncthreads();
    for (int o = 128; o > 0; o >>= 1) {
        if (t < o) s[t] += s[t + o];
        __syncthreads();
    }
    if (t == 0) bsum[blockIdx.x] = s[0];
}

// ---------------------------------------------------------------- scan B: exclusive scan of NA block sums
__global__ void scanB_kernel(int* __restrict__ bsum, int* __restrict__ total) {
    __shared__ int s[1024];
    int t = threadIdx.x;
    int v = (t < NA) ? bsum[t] : 0;
    s[t] = v;
    __syncthreads();
    for (int o = 1; o < 1024; o <<= 1) {
        int u = (t >= o) ? s[t - o] : 0;
        __syncthreads();
        s[t] += u;
        __syncthreads();
    }
    if (t < NA) bsum[t] = s[t] - v;             // exclusive block offset
    if (t == 1023) *total = s[t];
}

// ---------------------------------------------------------------- scan C: produce boff
__global__ void scanC_kernel(const int* __restrict__ src,
                             const int* __restrict__ bsum,
                             int* __restrict__ dst) {
    __shared__ int s[256];
    int t = threadIdx.x;
    int i = blockIdx.x * 256 + t;
    int v = (i < SCAN_L) ? src[i] : 0;
    s[t] = v;
    __syncthreads();
    for (int o = 1; o < 256; o <<= 1) {
        int u = (t >= o) ? s[t - o] : 0;
        __syncthreads();
        s[t] += u;
        __syncthreads();
    }
    if (i < SCAN_L) dst[i] = bsum[blockIdx.x] + s[t] - v;  // exclusive prefix
}

// ---------------------------------------------------------------- pass 3: bucket fill (LDS cursors)
__global__ void p3_fill_kernel(const int* __restrict__ ei,
                               const int* __restrict__ mode_p,
                               const int* __restrict__ boff,
                               int* __restrict__ ebuf) {
    __shared__ int cur[BINS];
    const int mode = *mode_p;
    int t = threadIdx.x;
    for (int j = t; j < BINS; j += blockDim.x) cur[j] = boff[j * BLK1 + blockIdx.x];
    __syncthreads();

    long long base = (long long)blockIdx.x * CHUNK;
    for (int k = t; k < CHUNK; k += blockDim.x) {
        long long e = base + k;
        if (e >= N_EDGES) break;
        int d = load_idx(ei, (long long)N_EDGES + e, mode);
        if ((unsigned)d >= (unsigned)N_NODES) continue;
        int s = load_idx(ei, e, mode);
        int bin = d / NPB;
        int ld = d - bin * NPB;
        int pos = atomicAdd(&cur[bin], 1);
        ebuf[pos] = s | (ld << 18);              // src:18 bits | local_dst:8 bits
    }
}

// ---------------------------------------------------------------- pass 5: per-bucket src-bin
// counting sort (LDS, in-place in ebuf) + degree -> dis + fp16 pack of h*dis (in-place).
// Sorting is PERF-ONLY (accumulation is order-independent); oversized buckets skip it.
__global__ void p5_sort_kernel(int* __restrict__ ebuf,
                               const int* __restrict__ boff,
                               const int* __restrict__ total,
                               float* __restrict__ hpad) {
    __shared__ int buf[SORT_CAP];
    __shared__ int hist[BINS];
    __shared__ int sc[BINS];
    __shared__ int cur[BINS];
    __shared__ int cnt[NPB];

    int b = blockIdx.x;
    int t = threadIdx.x;
    if (t < BINS) hist[t] = 0;
    if (t < NPB) cnt[t] = 0;
    __syncthreads();

    int start = boff[b * BLK1];
    int end = (b < BINS - 1) ? boff[(b + 1) * BLK1] : *total;
    int n = end - start;
    bool fit = (n <= SORT_CAP);

    for (int k = t; k < n; k += blockDim.x) {
        int v = ebuf[start + k];
        atomicAdd(&cnt[((unsigned)v) >> 18], 1);
        if (fit) {
            buf[k] = v;
            atomicAdd(&hist[(v & 0x3FFFF) / NPB], 1);
        }
    }
    __syncthreads();

    // dis = rsqrt(deg+1); pack h*dis to fp16 in-place (bytes 0-19 of the row)
    for (int j = t; j < NPB; j += blockDim.x) {
        int i = b * NPB + j;
        if (i >= N_NODES) continue;
        float dis = rsqrtf((float)(cnt[j] + 1));
        float* hr = hpad + (long long)i * HPAD;
        hr[10] = dis;
        unsigned pk[5];
#pragma unroll
        for (int k = 0; k < 5; ++k) {
            __half lo = __float2half(hr[2 * k] * dis);
            __half hi = __float2half(hr[2 * k + 1] * dis);
            pk[k] = ((unsigned)__half_as_ushort(hi) << 16) | (unsigned)__half_as_ushort(lo);
        }
        unsigned* rw = (unsigned*)hr;
#pragma unroll
        for (int k = 0; k < 5; ++k) rw[k] = pk[k];
    }
    if (!fit) return;

    // exclusive scan of hist (Hillis-Steele over 1024 entries, 1024 threads)
    sc[t] = hist[t];
    __syncthreads();
    for (int o = 1; o < BINS; o <<= 1) {
        int u = (t >= o) ? sc[t - o] : 0;
        __syncthreads();
        sc[t] += u;
        __syncthreads();
    }
    cur[t] = sc[t] - hist[t];
    __syncthreads();

    // scatter back to ebuf in src-bin order (source fully in LDS)
    for (int k = t; k < n; k += blockDim.x) {
        int v = buf[k];
        int pos = atomicAdd(&cur[(v & 0x3FFFF) / NPB], 1);
        ebuf[start + pos] = v;
    }
}

// ---------------------------------------------------------------- pass 4b: accumulate + epilogue
// 512 threads, ~8.9KB LDS, cap VGPR for 8 waves/SIMD (32 waves/CU at 4 blocks/CU).
__global__ void __launch_bounds__(512, 8)
p4b_acc_kernel(const int* __restrict__ ebuf,
               const int* __restrict__ boff,
               const int* __restrict__ total,
               const float* __restrict__ hpad,
               const float* __restrict__ b_gcn,
               const float* __restrict__ W_fc,
               const float* __restrict__ b_fc,
               float* __restrict__ out) {
    __shared__ float accs[NPB * ACCP];
    __shared__ float Wfs[F_HID * F_OUT];
    __shared__ float bfs[F_OUT];
    __shared__ float bgs[F_HID];

    int b = blockIdx.x;
    int t = threadIdx.x;

    for (int j = t; j < NPB * ACCP; j += blockDim.x) accs[j] = 0.0f;
    if (t < F_HID * F_OUT) Wfs[t] = W_fc[t];
    if (t < F_OUT) bfs[t] = b_fc[t];
    if (t < F_HID) bgs[t] = b_gcn[t];
    __syncthreads();

    int start = boff[b * BLK1];
    int end = (b < BINS - 1) ? boff[(b + 1) * BLK1] : *total;
    int n = end - start;

    // 4-edge batch per thread: 4 ebuf loads, then 8 gather loads, then 40 LDS atomics.
    for (int k0 = t * 4; k0 < n; k0 += blockDim.x * 4) {
        unsigned v[4];
        uint4 q[4];
        unsigned q4[4];
#pragma unroll
        for (int u = 0; u < 4; ++u) {
            int idx = start + min(k0 + u, n - 1);     // clamped: always-valid load
            v[u] = (unsigned)ebuf[idx];
        }
#pragma unroll
        for (int u = 0; u < 4; ++u) {
            const unsigned* row = (const unsigned*)(hpad + (long long)(v[u] & 0x3FFFF) * HPAD);
            q[u] = *(const uint4*)row;                // halves 0..7 (= h*dis fp16)
            q4[u] = row[4];                           // halves 8..9
        }
#pragma unroll
        for (int u = 0; u < 4; ++u) {
            if (k0 + u < n) {
                int ld = v[u] >> 18;
                float* a = &accs[ld * ACCP];
                float2 f01 = up2(q[u].x), f23 = up2(q[u].y);
                float2 f45 = up2(q[u].z), f67 = up2(q[u].w);
                float2 f89 = up2(q4[u]);
                atomicAdd(a + 0, f01.x); atomicAdd(a + 1, f01.y);
                atomicAdd(a + 2, f23.x); atomicAdd(a + 3, f23.y);
                atomicAdd(a + 4, f45.x); atomicAdd(a + 5, f45.y);
                atomicAdd(a + 6, f67.x); atomicAdd(a + 7, f67.y);
                atomicAdd(a + 8, f89.x); atomicAdd(a + 9, f89.y);
            }
        }
    }
    __syncthreads();

    float* hidden = out;                               // [N, F_HID]
    float4* o24 = reinterpret_cast<float4*>(out + (long long)N_NODES * F_HID);

    for (int j = t; j < NPB; j += blockDim.x) {
        int i = b * NPB + j;
        if (i >= N_NODES) continue;
        const float* hr = hpad + (long long)i * HPAD;
        float di = hr[10];
        const unsigned* row = (const unsigned*)hr;
        uint4 q = *(const uint4*)row;
        unsigned qq = row[4];
        float2 f01 = up2(q.x), f23 = up2(q.y), f45 = up2(q.z), f67 = up2(q.w), f89 = up2(qq);
        float hp[F_HID] = {f01.x, f01.y, f23.x, f23.y, f45.x, f45.y, f67.x, f67.y, f89.x, f89.y};

        float hv[F_HID];
#pragma unroll
        for (int f = 0; f < F_HID; ++f) {
            hv[f] = (accs[j * ACCP + f] + hp[f]) * di + bgs[f];   // (sum h'[s] + h'[i]) * dis[i] + b
            hidden[(long long)i * F_HID + f] = hv[f];
        }
        float4 o;
        float* op = &o.x;
#pragma unroll
        for (int jj = 0; jj < F_OUT; ++jj) {
            float vv = bfs[jj];
#pragma unroll
            for (int f = 0; f < F_HID; ++f) vv += hv[f] * Wfs[f * F_OUT + jj];
            op[jj] = fmaxf(vv, 0.0f);
        }
        o24[i] = o;
    }
}

// ================================================================ FALLBACK (atomic scatter)
__global__ void fb_init_kernel(const float* __restrict__ x, const float* __restrict__ Wg,
                               float* __restrict__ hpad, float* __restrict__ deg,
                               float* __restrict__ hidden) {
    __shared__ float Ws[F_IN * F_HID];
    for (int t = threadIdx.x; t < F_IN * F_HID; t += blockDim.x) Ws[t] = Wg[t];
    __syncthreads();
    int i = blockIdx.x * blockDim.x + threadIdx.x;
    if (i >= N_NODES) return;
    float acc[F_HID];
#pragma unroll
    for (int f = 0; f < F_HID; ++f) acc[f] = 0.0f;
    const float* xr = x + (long long)i * F_IN;
#pragma unroll
    for (int k = 0; k < F_IN; ++k) {
        float xv = xr[k];
#pragma unroll
        for (int f = 0; f < F_HID; ++f) acc[f] += xv * Ws[k * F_HID + f];
    }
    float* hr = hpad + (long long)i * HPAD;
#pragma unroll
    for (int f = 0; f < F_HID; ++f) hr[f] = acc[f];
    hr[10] = 0.0f; hr[11] = 0.0f;
    deg[i] = 1.0f;
    float* hd = hidden + (long long)i * F_HID;
#pragma unroll
    for (int f = 0; f < F_HID; ++f) hd[f] = 0.0f;
}

__global__ void fb_deg_kernel(const int* __restrict__ ei, const int* __restrict__ mode_p,
                              float* __restrict__ deg) {
    const int mode = *mode_p;
    long long e = (long long)blockIdx.x * blockDim.x + threadIdx.x;
    if (e >= N_EDGES) return;
    int d = load_idx(ei, (long long)N_EDGES + e, mode);
    if ((unsigned)d < (unsigned)N_NODES) atomicAdd(&deg[d], 1.0f);
}

__global__ void fb_scatter_kernel(const int* __restrict__ ei, const int* __restrict__ mode_p,
                                  const float* __restrict__ hpad, const float* __restrict__ deg,
                                  float* __restrict__ hidden) {
    const int mode = *mode_p;
    long long e = (long long)blockIdx.x * blockDim.x + threadIdx.x;
    if (e >= N_EDGES) return;
    int s = load_idx(ei, e, mode);
    int d = load_idx(ei, (long long)N_EDGES + e, mode);
    if ((unsigned)s >= (unsigned)N_NODES || (unsigned)d >= (unsigned)N_NODES) return;
    float norm = rsqrtf(deg[s]) * rsqrtf(deg[d]);
    const float4* h4 = reinterpret_cast<const float4*>(hpad + (long long)s * HPAD);
    float4 a = h4[0]; float4 b = h4[1]; float4 c = h4[2];
    float* o = hidden + (long long)d * F_HID;
    atomicAdd(o + 0, a.x * norm); atomicAdd(o + 1, a.y * norm);
    atomicAdd(o + 2, a.z * norm); atomicAdd(o + 3, a.w * norm);
    atomicAdd(o + 4, b.x * norm); atomicAdd(o + 5, b.y * norm);
    atomicAdd(o + 6, b.z * norm); atomicAdd(o + 7, b.w * norm);
    atomicAdd(o + 8, c.x * norm); atomicAdd(o + 9, c.y * norm);
}

__global__ void fb_finalize_kernel(const float* __restrict__ hpad, const float* __restrict__ deg,
                                   const float* __restrict__ b_gcn, const float* __restrict__ W_fc,
                                   const float* __restrict__ b_fc, float* __restrict__ out) {
    __shared__ float Wf[F_HID * F_OUT];
    __shared__ float bf_s[F_OUT];
    __shared__ float bg_s[F_HID];
    for (int t = threadIdx.x; t < F_HID * F_OUT; t += blockDim.x) Wf[t] = W_fc[t];
    if (threadIdx.x < F_OUT) bf_s[threadIdx.x] = b_fc[threadIdx.x];
    if (threadIdx.x < F_HID) bg_s[threadIdx.x] = b_gcn[threadIdx.x];
    __syncthreads();
    int i = blockIdx.x * blockDim.x + threadIdx.x;
    if (i >= N_NODES) return;
    float* hidden = out;
    float* o2 = out + (long long)N_NODES * F_HID;
    float inv = 1.0f / deg[i];
    const float* hr = hpad + (long long)i * HPAD;
    float* hd = hidden + (long long)i * F_HID;
    float hv[F_HID];
#pragma unroll
    for (int f = 0; f < F_HID; ++f) {
        hv[f] = hd[f] + hr[f] * inv + bg_s[f];
        hd[f] = hv[f];
    }
#pragma unroll
    for (int j = 0; j < F_OUT; ++j) {
        float o = bf_s[j];
#pragma unroll
        for (int f = 0; f < F_HID; ++f) o += hv[f] * Wf[f * F_OUT + j];
        o2[(long long)i * F_OUT + j] = fmaxf(o, 0.0f);
    }
}

// ---------------------------------------------------------------- launch
extern "C" void kernel_launch(void* const* d_in, const int* in_sizes, int n_in,
                              void* d_out, int out_size, void* d_ws, size_t ws_size,
                              hipStream_t stream) {
    const float* x  = (const float*)d_in[0];
    const int*   ei = (const int*)d_in[1];
    const float* Wg = (const float*)d_in[2];
    const float* bg = (const float*)d_in[3];
    const float* Wf = (const float*)d_in[4];
    const float* bf = (const float*)d_in[5];
    float* out = (float*)d_out;

    const int nblk_node = (N_NODES + 255) / 256;     // 782

    // sort-path ws layout
    float* hpad  = (float*)d_ws;                               // N*HPAD
    int*   bcnt  = (int*)(hpad + (size_t)N_NODES * HPAD);      // SCAN_L
    int*   boff  = bcnt + SCAN_L;                              // SCAN_L
    int*   bsum  = boff + SCAN_L;                              // 1024 (NA=784 used)
    int*   total = bsum + 1024;                                // 1
    int*   ebuf  = total + 1;                                  // N_EDGES
    int*   mode  = ebuf + N_EDGES;                             // 1
    size_t need = (size_t)((char*)(mode + 1) - (char*)d_ws);

    if (ws_size >= need) {
        detect_mode_kernel<<<1, 64, 0, stream>>>(ei, mode);
        init_kernel<<<nblk_node, 256, 0, stream>>>(x, Wg, hpad);
        p1_count_kernel<<<BLK1, 512, 0, stream>>>(ei, mode, bcnt);
        scanA_kernel<<<NA, 256, 0, stream>>>(bcnt, bsum);
        scanB_kernel<<<1, 1024, 0, stream>>>(bsum, total);
        scanC_kernel<<<NA, 256, 0, stream>>>(bcnt, bsum, boff);
        p3_fill_kernel<<<BLK1, 512, 0, stream>>>(ei, mode, boff, ebuf);
        p5_sort_kernel<<<BINS, 1024, 0, stream>>>(ebuf, boff, total, hpad);
        p4b_acc_kernel<<<BINS, 512, 0, stream>>>(ebuf, boff, total, hpad, bg, Wf, bf, out);
    } else {
        // fallback: atomic scatter (~10.4 MB)
        float* degf  = hpad + (size_t)N_NODES * HPAD;
        int*   mode2 = (int*)(degf + N_NODES);
        const int nblk_edge = (N_EDGES + 255) / 256;
        detect_mode_kernel<<<1, 64, 0, stream>>>(ei, mode2);
        fb_init_kernel<<<nblk_node, 256, 0, stream>>>(x, Wg, hpad, degf, out);
        fb_deg_kernel<<<nblk_edge, 256, 0, stream>>>(ei, mode2, degf);
        fb_scatter_kernel<<<nblk_edge, 256, 0, stream>>>(ei, mode2, hpad, degf, out);
        fb_finalize_kernel<<<nblk_node, 256, 0, stream>>>(hpad, degf, bg, Wf, bf, out);
    }
}

// Round 7
// 299.270 us; speedup vs baseline: 1.6141x; 1.6141x over previous
//
#include <hip/hip_runtime.h>
#include <hip/hip_fp16.h>

#define N_NODES 200000
#define N_EDGES 6400000
#define F_IN 34
#define F_HID 10
#define F_OUT 4
#define HPAD 12              // fb path only: 48B fp32 rows
#define BINS 782             // dst buckets
#define NPB 256              // nodes per bucket: 782*256 = 200192 >= N
#define CHUNK 32768
#define BLK1 ((N_EDGES + CHUNK - 1) / CHUNK)    // 196
#define SCAN_L (BINS * BLK1)                    // 153272
#define NA ((SCAN_L + 255) / 256)               // 599
#define ACCP 11              // fallback-arm LDS acc padding
#define SORT_CAP 12288       // 48KB LDS; bucket avg 8184, sigma~90 -> 45 sigma margin

// ---------------------------------------------------------------- helpers
__device__ __forceinline__ float2 up2(unsigned u) {
    __half2 h = *reinterpret_cast<const __half2*>(&u);
    return __half22float2(h);
}

// ---------------------------------------------------------------- mode detect
// int64 edge_index => every odd 32-bit word is zero (values < 2^31).
__global__ void detect_mode_kernel(const int* __restrict__ ei, int* __restrict__ mode) {
    int t = threadIdx.x;                 // 64 threads
    int v = ei[2 * t + 1];
    unsigned long long b = __ballot(v != 0);
    if (t == 0) *mode = (b == 0ull) ? 1 : 0;
}

__device__ __forceinline__ int load_idx(const int* ei, long long elem, int mode) {
    return mode ? ei[2 * elem] : ei[elem];
}

// ---------------------------------------------------------------- pass 1: bucket counts (LDS hist)
__global__ void p1_count_kernel(const int* __restrict__ ei,
                                const int* __restrict__ mode_p,
                                int* __restrict__ bcnt) {
    __shared__ int hist[BINS];
    const int mode = *mode_p;
    int t = threadIdx.x;
    for (int j = t; j < BINS; j += blockDim.x) hist[j] = 0;
    __syncthreads();

    long long base = (long long)blockIdx.x * CHUNK;
    for (int k = t; k < CHUNK; k += blockDim.x) {
        long long e = base + k;
        if (e >= N_EDGES) break;
        int d = load_idx(ei, (long long)N_EDGES + e, mode);
        if ((unsigned)d < (unsigned)N_NODES) atomicAdd(&hist[d >> 8], 1);
    }
    __syncthreads();
    for (int j = t; j < BINS; j += blockDim.x)
        bcnt[j * BLK1 + blockIdx.x] = hist[j];   // bin-major
}

// ---------------------------------------------------------------- scan A: per-block sums
__global__ void scanA_kernel(const int* __restrict__ src, int* __restrict__ bsum) {
    __shared__ int s[256];
    int t = threadIdx.x;
    int i = blockIdx.x * 256 + t;
    s[t] = (i < SCAN_L) ? src[i] : 0;
    __syncthreads();
    for (int o = 128; o > 0; o >>= 1) {
        if (t < o) s[t] += s[t + o];
        __syncthreads();
    }
    if (t == 0) bsum[blockIdx.x] = s[0];
}

// ---------------------------------------------------------------- scan B: exclusive scan of NA block sums
__global__ void scanB_kernel(int* __restrict__ bsum, int* __restrict__ total) {
    __shared__ int s[1024];
    int t = threadIdx.x;
    int v = (t < NA) ? bsum[t] : 0;
    s[t] = v;
    __syncthreads();
    for (int o = 1; o < 1024; o <<= 1) {
        int u = (t >= o) ? s[t - o] : 0;
        __syncthreads();
        s[t] += u;
        __syncthreads();
    }
    if (t < NA) bsum[t] = s[t] - v;             // exclusive block offset
    if (t == 1023) *total = s[t];
}

// ---------------------------------------------------------------- scan C: produce boff
__global__ void scanC_kernel(const int* __restrict__ src,
                             const int* __restrict__ bsum,
                             int* __restrict__ dst) {
    __shared__ int s[256];
    int t = threadIdx.x;
    int i = blockIdx.x * 256 + t;
    int v = (i < SCAN_L) ? src[i] : 0;
    s[t] = v;
    __syncthreads();
    for (int o = 1; o < 256; o <<= 1) {
        int u = (t >= o) ? s[t - o] : 0;
        __syncthreads();
        s[t] += u;
        __syncthreads();
    }
    if (i < SCAN_L) dst[i] = bsum[blockIdx.x] + s[t] - v;  // exclusive prefix
}

// ---------------------------------------------------------------- pass 3: bucket fill (LDS cursors)
__global__ void p3_fill_kernel(const int* __restrict__ ei,
                               const int* __restrict__ mode_p,
                               const int* __restrict__ boff,
                               int* __restrict__ ebuf) {
    __shared__ int cur[BINS];
    const int mode = *mode_p;
    int t = threadIdx.x;
    for (int j = t; j < BINS; j += blockDim.x) cur[j] = boff[j * BLK1 + blockIdx.x];
    __syncthreads();

    long long base = (long long)blockIdx.x * CHUNK;
    for (int k = t; k < CHUNK; k += blockDim.x) {
        long long e = base + k;
        if (e >= N_EDGES) break;
        int d = load_idx(ei, (long long)N_EDGES + e, mode);
        if ((unsigned)d >= (unsigned)N_NODES) continue;
        int s = load_idx(ei, e, mode);
        s = min(max(s, 0), N_NODES - 1);         // memory-safety clamp (input always valid)
        int bin = d >> 8;
        int ld = d & 255;
        int pos = atomicAdd(&cur[bin], 1);
        ebuf[pos] = s | (ld << 18);              // src:18 bits | local_dst:8 bits
    }
}

// ---------------------------------------------------------------- pass 5: per-bucket counting
// sort by LOCAL DST (LDS, in-place in ebuf) -> full dst-sorted edge array + nodeoff,
// plus per-node degree -> disf. Sort is required for p4b's fast arm; flag[b] records it.
__global__ void p5_sort_kernel(int* __restrict__ ebuf,
                               const int* __restrict__ boff,
                               const int* __restrict__ total,
                               float* __restrict__ disf,
                               int* __restrict__ nodeoff,
                               int* __restrict__ flag) {
    __shared__ int buf[SORT_CAP];
    __shared__ int cnt[NPB];
    __shared__ int sc[NPB];
    __shared__ int cur[NPB];

    int b = blockIdx.x;
    int t = threadIdx.x;
    if (t < NPB) cnt[t] = 0;
    __syncthreads();

    int start = boff[b * BLK1];
    int end = (b < BINS - 1) ? boff[(b + 1) * BLK1] : *total;
    int n = end - start;
    bool fit = (n <= SORT_CAP);

    for (int k = t; k < n; k += blockDim.x) {
        int v = ebuf[start + k];
        atomicAdd(&cnt[((unsigned)v) >> 18], 1);
        if (fit) buf[k] = v;
    }
    __syncthreads();

    // exclusive scan of cnt (256 entries, threads t<256)
    if (t < NPB) sc[t] = cnt[t];
    __syncthreads();
    for (int o = 1; o < NPB; o <<= 1) {
        int u = (t < NPB && t >= o) ? sc[t - o] : 0;
        __syncthreads();
        if (t < NPB) sc[t] += u;
        __syncthreads();
    }
    if (t < NPB) {
        int excl = sc[t] - cnt[t];
        nodeoff[b * NPB + t] = start + excl;
        cur[t] = start + excl;               // ABSOLUTE cursor
        int i = b * NPB + t;
        if (i < N_NODES) disf[i] = rsqrtf((float)(cnt[t] + 1));   // +1 self-loop
    }
    if (b == BINS - 1 && t == 0) nodeoff[BINS * NPB] = end;
    if (t == 0) flag[b] = fit ? 1 : 0;
    __syncthreads();

    if (!fit) return;
    // scatter back to ebuf grouped by local dst (source fully in LDS).
    // cur[] is ABSOLUTE -> write ebuf[pos], NOT ebuf[start+pos] (round-6 bug).
    for (int k = t; k < n; k += blockDim.x) {
        int v = buf[k];
        int pos = atomicAdd(&cur[((unsigned)v) >> 18], 1);
        ebuf[pos] = v;
    }
}

// ---------------------------------------------------------------- init2: h = (x @ W) * dis,
// packed fp16 into compact SoA table (random-gather footprint = 4MB, L2-resident per XCD).
__global__ void init2_kernel(const float* __restrict__ x,
                             const float* __restrict__ Wg,
                             const float* __restrict__ disf,
                             uint4* __restrict__ hpkA,
                             unsigned* __restrict__ hpkB) {
    __shared__ float Ws[F_IN * F_HID];
    for (int t = threadIdx.x; t < F_IN * F_HID; t += blockDim.x) Ws[t] = Wg[t];
    __syncthreads();

    int i = blockIdx.x * blockDim.x + threadIdx.x;
    if (i >= N_NODES) return;

    float acc[F_HID];
#pragma unroll
    for (int f = 0; f < F_HID; ++f) acc[f] = 0.0f;

    const float* xr = x + (long long)i * F_IN;
#pragma unroll
    for (int k = 0; k < F_IN; ++k) {
        float xv = xr[k];
#pragma unroll
        for (int f = 0; f < F_HID; ++f) acc[f] += xv * Ws[k * F_HID + f];
    }

    float di = disf[i];
    unsigned pk[5];
#pragma unroll
    for (int k = 0; k < 5; ++k) {
        __half lo = __float2half(acc[2 * k] * di);
        __half hi = __float2half(acc[2 * k + 1] * di);
        pk[k] = ((unsigned)__half_as_ushort(hi) << 16) | (unsigned)__half_as_ushort(lo);
    }
    hpkA[i] = make_uint4(pk[0], pk[1], pk[2], pk[3]);
    hpkB[i] = pk[4];
}

// ---------------------------------------------------------------- pass 4b: per-node register
// gather-accumulate (NO atomics) + fused epilogue. One thread per node.
__global__ void p4b_acc_kernel(const int* __restrict__ ebuf,
                               const int* __restrict__ nodeoff,
                               const int* __restrict__ flag,
                               const uint4* __restrict__ hpkA,
                               const unsigned* __restrict__ hpkB,
                               const float* __restrict__ disf,
                               const float* __restrict__ b_gcn,
                               const float* __restrict__ W_fc,
                               const float* __restrict__ b_fc,
                               float* __restrict__ out) {
    __shared__ float accs[NPB * ACCP];   // fallback arm only
    __shared__ float Wfs[F_HID * F_OUT];
    __shared__ float bfs[F_OUT];
    __shared__ float bgs[F_HID];

    int b = blockIdx.x;
    int t = threadIdx.x;
    if (t < F_HID * F_OUT) Wfs[t] = W_fc[t];
    if (t < F_OUT) bfs[t] = b_fc[t];
    if (t < F_HID) bgs[t] = b_gcn[t];
    __syncthreads();

    float* hidden = out;                               // [N, F_HID]
    float4* o24 = reinterpret_cast<float4*>(out + (long long)N_NODES * F_HID);

    int i = b * NPB + t;
    bool valid = (i < N_NODES);
    float acc[F_HID];
#pragma unroll
    for (int f = 0; f < F_HID; ++f) acc[f] = 0.0f;

    if (flag[b]) {
        // ---------- fast arm: dst-sorted, register accumulation ----------
        int rs = valid ? nodeoff[i] : 0;
        int re = valid ? nodeoff[i + 1] : 0;
        for (int k = rs; k < re; k += 4) {
            unsigned v[4]; uint4 qa[4]; unsigned qb[4];
#pragma unroll
            for (int u = 0; u < 4; ++u) v[u] = (unsigned)ebuf[min(k + u, re - 1)];
#pragma unroll
            for (int u = 0; u < 4; ++u) {
                int s = v[u] & 0x3FFFF;
                qa[u] = hpkA[s];
                qb[u] = hpkB[s];
            }
#pragma unroll
            for (int u = 0; u < 4; ++u) {
                if (k + u < re) {
                    float2 f01 = up2(qa[u].x), f23 = up2(qa[u].y);
                    float2 f45 = up2(qa[u].z), f67 = up2(qa[u].w);
                    float2 f89 = up2(qb[u]);
                    acc[0] += f01.x; acc[1] += f01.y;
                    acc[2] += f23.x; acc[3] += f23.y;
                    acc[4] += f45.x; acc[5] += f45.y;
                    acc[6] += f67.x; acc[7] += f67.y;
                    acc[8] += f89.x; acc[9] += f89.y;
                }
            }
        }
    } else {
        // ---------- fallback arm: unsorted bucket, LDS atomics (never taken for valid input) ----
        for (int j = t; j < NPB * ACCP; j += blockDim.x) accs[j] = 0.0f;
        __syncthreads();
        int start = nodeoff[b * NPB];
        int end = nodeoff[(b + 1) * NPB];
        for (int e = start + t; e < end; e += blockDim.x) {
            unsigned v = (unsigned)ebuf[e];
            int s = v & 0x3FFFF;
            int ld = v >> 18;
            uint4 qa = hpkA[s]; unsigned qb = hpkB[s];
            float2 f01 = up2(qa.x), f23 = up2(qa.y), f45 = up2(qa.z), f67 = up2(qa.w), f89 = up2(qb);
            float* a = &accs[ld * ACCP];
            atomicAdd(a + 0, f01.x); atomicAdd(a + 1, f01.y);
            atomicAdd(a + 2, f23.x); atomicAdd(a + 3, f23.y);
            atomicAdd(a + 4, f45.x); atomicAdd(a + 5, f45.y);
            atomicAdd(a + 6, f67.x); atomicAdd(a + 7, f67.y);
            atomicAdd(a + 8, f89.x); atomicAdd(a + 9, f89.y);
        }
        __syncthreads();
#pragma unroll
        for (int f = 0; f < F_HID; ++f) acc[f] = accs[t * ACCP + f];
    }

    if (!valid) return;

    uint4 qa = hpkA[i]; unsigned qb = hpkB[i];
    float di = disf[i];
    float2 f01 = up2(qa.x), f23 = up2(qa.y), f45 = up2(qa.z), f67 = up2(qa.w), f89 = up2(qb);
    float hp[F_HID] = {f01.x, f01.y, f23.x, f23.y, f45.x, f45.y, f67.x, f67.y, f89.x, f89.y};

    float hv[F_HID];
#pragma unroll
    for (int f = 0; f < F_HID; ++f) {
        hv[f] = (acc[f] + hp[f]) * di + bgs[f];    // (sum_nbrs h' + h'[i]) * dis[i] + b
        hidden[(long long)i * F_HID + f] = hv[f];
    }
    float4 o;
    float* op = &o.x;
#pragma unroll
    for (int jj = 0; jj < F_OUT; ++jj) {
        float vv = bfs[jj];
#pragma unroll
        for (int f = 0; f < F_HID; ++f) vv += hv[f] * Wfs[f * F_OUT + jj];
        op[jj] = fmaxf(vv, 0.0f);
    }
    o24[i] = o;
}

// ================================================================ FALLBACK (atomic scatter, small ws)
__global__ void fb_init_kernel(const float* __restrict__ x, const float* __restrict__ Wg,
                               float* __restrict__ hpad, float* __restrict__ deg,
                               float* __restrict__ hidden) {
    __shared__ float Ws[F_IN * F_HID];
    for (int t = threadIdx.x; t < F_IN * F_HID; t += blockDim.x) Ws[t] = Wg[t];
    __syncthreads();
    int i = blockIdx.x * blockDim.x + threadIdx.x;
    if (i >= N_NODES) return;
    float acc[F_HID];
#pragma unroll
    for (int f = 0; f < F_HID; ++f) acc[f] = 0.0f;
    const float* xr = x + (long long)i * F_IN;
#pragma unroll
    for (int k = 0; k < F_IN; ++k) {
        float xv = xr[k];
#pragma unroll
        for (int f = 0; f < F_HID; ++f) acc[f] += xv * Ws[k * F_HID + f];
    }
    float* hr = hpad + (long long)i * HPAD;
#pragma unroll
    for (int f = 0; f < F_HID; ++f) hr[f] = acc[f];
    hr[10] = 0.0f; hr[11] = 0.0f;
    deg[i] = 1.0f;
    float* hd = hidden + (long long)i * F_HID;
#pragma unroll
    for (int f = 0; f < F_HID; ++f) hd[f] = 0.0f;
}

__global__ void fb_deg_kernel(const int* __restrict__ ei, const int* __restrict__ mode_p,
                              float* __restrict__ deg) {
    const int mode = *mode_p;
    long long e = (long long)blockIdx.x * blockDim.x + threadIdx.x;
    if (e >= N_EDGES) return;
    int d = load_idx(ei, (long long)N_EDGES + e, mode);
    if ((unsigned)d < (unsigned)N_NODES) atomicAdd(&deg[d], 1.0f);
}

__global__ void fb_scatter_kernel(const int* __restrict__ ei, const int* __restrict__ mode_p,
                                  const float* __restrict__ hpad, const float* __restrict__ deg,
                                  float* __restrict__ hidden) {
    const int mode = *mode_p;
    long long e = (long long)blockIdx.x * blockDim.x + threadIdx.x;
    if (e >= N_EDGES) return;
    int s = load_idx(ei, e, mode);
    int d = load_idx(ei, (long long)N_EDGES + e, mode);
    if ((unsigned)s >= (unsigned)N_NODES || (unsigned)d >= (unsigned)N_NODES) return;
    float norm = rsqrtf(deg[s]) * rsqrtf(deg[d]);
    const float4* h4 = reinterpret_cast<const float4*>(hpad + (long long)s * HPAD);
    float4 a = h4[0]; float4 b = h4[1]; float4 c = h4[2];
    float* o = hidden + (long long)d * F_HID;
    atomicAdd(o + 0, a.x * norm); atomicAdd(o + 1, a.y * norm);
    atomicAdd(o + 2, a.z * norm); atomicAdd(o + 3, a.w * norm);
    atomicAdd(o + 4, b.x * norm); atomicAdd(o + 5, b.y * norm);
    atomicAdd(o + 6, b.z * norm); atomicAdd(o + 7, b.w * norm);
    atomicAdd(o + 8, c.x * norm); atomicAdd(o + 9, c.y * norm);
}

__global__ void fb_finalize_kernel(const float* __restrict__ hpad, const float* __restrict__ deg,
                                   const float* __restrict__ b_gcn, const float* __restrict__ W_fc,
                                   const float* __restrict__ b_fc, float* __restrict__ out) {
    __shared__ float Wf[F_HID * F_OUT];
    __shared__ float bf_s[F_OUT];
    __shared__ float bg_s[F_HID];
    for (int t = threadIdx.x; t < F_HID * F_OUT; t += blockDim.x) Wf[t] = W_fc[t];
    if (threadIdx.x < F_OUT) bf_s[threadIdx.x] = b_fc[threadIdx.x];
    if (threadIdx.x < F_HID) bg_s[threadIdx.x] = b_gcn[threadIdx.x];
    __syncthreads();
    int i = blockIdx.x * blockDim.x + threadIdx.x;
    if (i >= N_NODES) return;
    float* hidden = out;
    float* o2 = out + (long long)N_NODES * F_HID;
    float inv = 1.0f / deg[i];
    const float* hr = hpad + (long long)i * HPAD;
    float* hd = hidden + (long long)i * F_HID;
    float hv[F_HID];
#pragma unroll
    for (int f = 0; f < F_HID; ++f) {
        hv[f] = hd[f] + hr[f] * inv + bg_s[f];
        hd[f] = hv[f];
    }
#pragma unroll
    for (int j = 0; j < F_OUT; ++j) {
        float o = bf_s[j];
#pragma unroll
        for (int f = 0; f < F_HID; ++f) o += hv[f] * Wf[f * F_OUT + j];
        o2[(long long)i * F_OUT + j] = fmaxf(o, 0.0f);
    }
}

// ---------------------------------------------------------------- launch
extern "C" void kernel_launch(void* const* d_in, const int* in_sizes, int n_in,
                              void* d_out, int out_size, void* d_ws, size_t ws_size,
                              hipStream_t stream) {
    const float* x  = (const float*)d_in[0];
    const int*   ei = (const int*)d_in[1];
    const float* Wg = (const float*)d_in[2];
    const float* bg = (const float*)d_in[3];
    const float* Wf = (const float*)d_in[4];
    const float* bf = (const float*)d_in[5];
    float* out = (float*)d_out;

    const int nblk_node = (N_NODES + 255) / 256;     // 782

    // main ws layout (~32.4 MB)
    uint4*    hpkA    = (uint4*)d_ws;                               // N (16B each)
    unsigned* hpkB    = (unsigned*)(hpkA + N_NODES);                // N
    float*    disf    = (float*)(hpkB + N_NODES);                   // N
    int*      bcnt    = (int*)(disf + N_NODES);                     // SCAN_L
    int*      boff    = bcnt + SCAN_L;                              // SCAN_L
    int*      bsum    = boff + SCAN_L;                              // 1024
    int*      total   = bsum + 1024;                                // 1
    int*      nodeoff = total + 1;                                  // BINS*NPB+1
    int*      flag    = nodeoff + BINS * NPB + 1;                   // BINS
    int*      ebuf    = flag + BINS;                                // N_EDGES
    int*      mode    = ebuf + N_EDGES;                             // 1
    size_t need = (size_t)((char*)(mode + 1) - (char*)d_ws);

    if (ws_size >= need) {
        detect_mode_kernel<<<1, 64, 0, stream>>>(ei, mode);
        p1_count_kernel<<<BLK1, 512, 0, stream>>>(ei, mode, bcnt);
        scanA_kernel<<<NA, 256, 0, stream>>>(bcnt, bsum);
        scanB_kernel<<<1, 1024, 0, stream>>>(bsum, total);
        scanC_kernel<<<NA, 256, 0, stream>>>(bcnt, bsum, boff);
        p3_fill_kernel<<<BLK1, 512, 0, stream>>>(ei, mode, boff, ebuf);
        p5_sort_kernel<<<BINS, 512, 0, stream>>>(ebuf, boff, total, disf, nodeoff, flag);
        init2_kernel<<<nblk_node, 256, 0, stream>>>(x, Wg, disf, hpkA, hpkB);
        p4b_acc_kernel<<<BINS, NPB, 0, stream>>>(ebuf, nodeoff, flag, hpkA, hpkB, disf,
                                                 bg, Wf, bf, out);
    } else {
        // fallback: atomic scatter (~10.4 MB)
        float* hpad  = (float*)d_ws;
        float* degf  = hpad + (size_t)N_NODES * HPAD;
        int*   mode2 = (int*)(degf + N_NODES);
        const int nblk_edge = (N_EDGES + 255) / 256;
        detect_mode_kernel<<<1, 64, 0, stream>>>(ei, mode2);
        fb_init_kernel<<<nblk_node, 256, 0, stream>>>(x, Wg, hpad, degf, out);
        fb_deg_kernel<<<nblk_edge, 256, 0, stream>>>(ei, mode2, degf);
        fb_scatter_kernel<<<nblk_edge, 256, 0, stream>>>(ei, mode2, hpad, degf, out);
        fb_finalize_kernel<<<nblk_node, 256, 0, stream>>>(hpad, degf, bg, Wf, bf, out);
    }
}

// Round 8
// 262.956 us; speedup vs baseline: 1.8370x; 1.1381x over previous
//
#include <hip/hip_runtime.h>
#include <hip/hip_fp16.h>

#define N_NODES 200000
#define N_EDGES 6400000
#define F_IN 34
#define F_HID 10
#define F_OUT 4
#define HPAD 12              // fb path only: 48B fp32 rows
#define BINS 782             // dst buckets
#define NPB 256              // nodes per bucket: 782*256 = 200192 >= N
#define CHUNK 19456
#define BLK1 ((N_EDGES + CHUNK - 1) / CHUNK)    // 329
#define SCAN_L (BINS * BLK1)                    // 257278
#define NA ((SCAN_L + 255) / 256)               // 1006 (<= 1024 for scanB)
#define ACCP 11              // fallback-arm LDS acc padding
#define SORT_CAP 12288       // 48KB LDS; bucket avg 8184, sigma~90 -> 45 sigma margin

// ---------------------------------------------------------------- helpers
__device__ __forceinline__ float2 up2(unsigned u) {
    __half2 h = *reinterpret_cast<const __half2*>(&u);
    return __half22float2(h);
}

// ---------------------------------------------------------------- mode detect
// int64 edge_index => every odd 32-bit word is zero (values < 2^31).
__global__ void detect_mode_kernel(const int* __restrict__ ei, int* __restrict__ mode) {
    int t = threadIdx.x;                 // 64 threads
    int v = ei[2 * t + 1];
    unsigned long long b = __ballot(v != 0);
    if (t == 0) *mode = (b == 0ull) ? 1 : 0;
}

__device__ __forceinline__ int load_idx(const int* ei, long long elem, int mode) {
    return mode ? ei[2 * elem] : ei[elem];
}

// ---------------------------------------------------------------- pass 1: bucket counts (LDS hist)
__global__ void p1_count_kernel(const int* __restrict__ ei,
                                const int* __restrict__ mode_p,
                                int* __restrict__ bcnt) {
    __shared__ int hist[BINS];
    const int mode = *mode_p;
    int t = threadIdx.x;
    for (int j = t; j < BINS; j += blockDim.x) hist[j] = 0;
    __syncthreads();

    long long base = (long long)blockIdx.x * CHUNK;
    for (int k = t; k < CHUNK; k += blockDim.x) {
        long long e = base + k;
        if (e >= N_EDGES) break;
        int d = load_idx(ei, (long long)N_EDGES + e, mode);
        if ((unsigned)d < (unsigned)N_NODES) atomicAdd(&hist[d >> 8], 1);
    }
    __syncthreads();
    for (int j = t; j < BINS; j += blockDim.x)
        bcnt[j * BLK1 + blockIdx.x] = hist[j];   // bin-major
}

// ---------------------------------------------------------------- scan A: per-block sums
__global__ void scanA_kernel(const int* __restrict__ src, int* __restrict__ bsum) {
    __shared__ int s[256];
    int t = threadIdx.x;
    int i = blockIdx.x * 256 + t;
    s[t] = (i < SCAN_L) ? src[i] : 0;
    __syncthreads();
    for (int o = 128; o > 0; o >>= 1) {
        if (t < o) s[t] += s[t + o];
        __syncthreads();
    }
    if (t == 0) bsum[blockIdx.x] = s[0];
}

// ---------------------------------------------------------------- scan B: exclusive scan of NA block sums
__global__ void scanB_kernel(int* __restrict__ bsum, int* __restrict__ total) {
    __shared__ int s[1024];
    int t = threadIdx.x;
    int v = (t < NA) ? bsum[t] : 0;
    s[t] = v;
    __syncthreads();
    for (int o = 1; o < 1024; o <<= 1) {
        int u = (t >= o) ? s[t - o] : 0;
        __syncthreads();
        s[t] += u;
        __syncthreads();
    }
    if (t < NA) bsum[t] = s[t] - v;             // exclusive block offset
    if (t == 1023) *total = s[t];
}

// ---------------------------------------------------------------- scan C: produce boff
__global__ void scanC_kernel(const int* __restrict__ src,
                             const int* __restrict__ bsum,
                             int* __restrict__ dst) {
    __shared__ int s[256];
    int t = threadIdx.x;
    int i = blockIdx.x * 256 + t;
    int v = (i < SCAN_L) ? src[i] : 0;
    s[t] = v;
    __syncthreads();
    for (int o = 1; o < 256; o <<= 1) {
        int u = (t >= o) ? s[t - o] : 0;
        __syncthreads();
        s[t] += u;
        __syncthreads();
    }
    if (i < SCAN_L) dst[i] = bsum[blockIdx.x] + s[t] - v;  // exclusive prefix
}

// ---------------------------------------------------------------- pass 3: bucket fill (LDS cursors)
__global__ void p3_fill_kernel(const int* __restrict__ ei,
                               const int* __restrict__ mode_p,
                               const int* __restrict__ boff,
                               int* __restrict__ ebuf) {
    __shared__ int cur[BINS];
    const int mode = *mode_p;
    int t = threadIdx.x;
    for (int j = t; j < BINS; j += blockDim.x) cur[j] = boff[j * BLK1 + blockIdx.x];
    __syncthreads();

    long long base = (long long)blockIdx.x * CHUNK;
    for (int k = t; k < CHUNK; k += blockDim.x) {
        long long e = base + k;
        if (e >= N_EDGES) break;
        int d = load_idx(ei, (long long)N_EDGES + e, mode);
        if ((unsigned)d >= (unsigned)N_NODES) continue;
        int s = load_idx(ei, e, mode);
        s = min(max(s, 0), N_NODES - 1);         // memory-safety clamp (input always valid)
        int bin = d >> 8;
        int ld = d & 255;
        int pos = atomicAdd(&cur[bin], 1);
        ebuf[pos] = s | (ld << 18);              // src:18 bits | local_dst:8 bits
    }
}

// ---------------------------------------------------------------- pass 5: per-bucket counting
// sort by LOCAL DST (LDS, in-place in ebuf) -> full dst-sorted edge array + nodeoff,
// plus per-node degree -> disf. Sort is required for p4b's fast arm; flag[b] records it.
__global__ void p5_sort_kernel(int* __restrict__ ebuf,
                               const int* __restrict__ boff,
                               const int* __restrict__ total,
                               float* __restrict__ disf,
                               int* __restrict__ nodeoff,
                               int* __restrict__ flag) {
    __shared__ int buf[SORT_CAP];
    __shared__ int cnt[NPB];
    __shared__ int sc[NPB];
    __shared__ int cur[NPB];

    int b = blockIdx.x;
    int t = threadIdx.x;
    if (t < NPB) cnt[t] = 0;
    __syncthreads();

    int start = boff[b * BLK1];
    int end = (b < BINS - 1) ? boff[(b + 1) * BLK1] : *total;
    int n = end - start;
    bool fit = (n <= SORT_CAP);

    for (int k = t; k < n; k += blockDim.x) {
        int v = ebuf[start + k];
        atomicAdd(&cnt[((unsigned)v) >> 18], 1);
        if (fit) buf[k] = v;
    }
    __syncthreads();

    // exclusive scan of cnt (256 entries, threads t<256)
    if (t < NPB) sc[t] = cnt[t];
    __syncthreads();
    for (int o = 1; o < NPB; o <<= 1) {
        int u = (t < NPB && t >= o) ? sc[t - o] : 0;
        __syncthreads();
        if (t < NPB) sc[t] += u;
        __syncthreads();
    }
    if (t < NPB) {
        int excl = sc[t] - cnt[t];
        nodeoff[b * NPB + t] = start + excl;
        cur[t] = start + excl;               // ABSOLUTE cursor
        int i = b * NPB + t;
        if (i < N_NODES) disf[i] = rsqrtf((float)(cnt[t] + 1));   // +1 self-loop
    }
    if (b == BINS - 1 && t == 0) nodeoff[BINS * NPB] = end;
    if (t == 0) flag[b] = fit ? 1 : 0;
    __syncthreads();

    if (!fit) return;
    // scatter back to ebuf grouped by local dst (source fully in LDS).
    // cur[] is ABSOLUTE -> write ebuf[pos].
    for (int k = t; k < n; k += blockDim.x) {
        int v = buf[k];
        int pos = atomicAdd(&cur[((unsigned)v) >> 18], 1);
        ebuf[pos] = v;
    }
}

// ---------------------------------------------------------------- init2: h = (x @ W) * dis,
// packed fp16 into compact SoA table (random-gather footprint = 4MB).
__global__ void init2_kernel(const float* __restrict__ x,
                             const float* __restrict__ Wg,
                             const float* __restrict__ disf,
                             uint4* __restrict__ hpkA,
                             unsigned* __restrict__ hpkB) {
    __shared__ float Ws[F_IN * F_HID];
    for (int t = threadIdx.x; t < F_IN * F_HID; t += blockDim.x) Ws[t] = Wg[t];
    __syncthreads();

    int i = blockIdx.x * blockDim.x + threadIdx.x;
    if (i >= N_NODES) return;

    float acc[F_HID];
#pragma unroll
    for (int f = 0; f < F_HID; ++f) acc[f] = 0.0f;

    const float* xr = x + (long long)i * F_IN;
#pragma unroll
    for (int k = 0; k < F_IN; ++k) {
        float xv = xr[k];
#pragma unroll
        for (int f = 0; f < F_HID; ++f) acc[f] += xv * Ws[k * F_HID + f];
    }

    float di = disf[i];
    unsigned pk[5];
#pragma unroll
    for (int k = 0; k < 5; ++k) {
        __half lo = __float2half(acc[2 * k] * di);
        __half hi = __float2half(acc[2 * k + 1] * di);
        pk[k] = ((unsigned)__half_as_ushort(hi) << 16) | (unsigned)__half_as_ushort(lo);
    }
    hpkA[i] = make_uint4(pk[0], pk[1], pk[2], pk[3]);
    hpkB[i] = pk[4];
}

// ---------------------------------------------------------------- pass 4b: per-node register
// gather-accumulate (NO atomics), 2 THREADS PER NODE (parity-split edge list, batch-4 each,
// shfl_xor pair-combine) + fused epilogue on even lanes.
__global__ void __launch_bounds__(512, 8)
p4b_acc_kernel(const int* __restrict__ ebuf,
               const int* __restrict__ nodeoff,
               const int* __restrict__ flag,
               const uint4* __restrict__ hpkA,
               const unsigned* __restrict__ hpkB,
               const float* __restrict__ disf,
               const float* __restrict__ b_gcn,
               const float* __restrict__ W_fc,
               const float* __restrict__ b_fc,
               float* __restrict__ out) {
    __shared__ float accs[NPB * ACCP];   // fallback arm only
    __shared__ float Wfs[F_HID * F_OUT];
    __shared__ float bfs[F_OUT];
    __shared__ float bgs[F_HID];

    int b = blockIdx.x;
    int t = threadIdx.x;                 // 0..511
    int jl = t >> 1;                     // local node 0..255
    int par = t & 1;                     // parity within node pair
    if (t < F_HID * F_OUT) Wfs[t] = W_fc[t];
    if (t < F_OUT) bfs[t] = b_fc[t];
    if (t < F_HID) bgs[t] = b_gcn[t];
    __syncthreads();

    float* hidden = out;                               // [N, F_HID]
    float4* o24 = reinterpret_cast<float4*>(out + (long long)N_NODES * F_HID);

    int i = b * NPB + jl;
    bool valid = (i < N_NODES);
    float acc[F_HID];
#pragma unroll
    for (int f = 0; f < F_HID; ++f) acc[f] = 0.0f;

    if (flag[b]) {
        // ---------- fast arm: dst-sorted, register accumulation ----------
        int rs = valid ? nodeoff[i] : 0;
        int re = valid ? nodeoff[i + 1] : 0;
        for (int k = rs + par; k < re; k += 8) {      // this thread: k, k+2, k+4, k+6
            unsigned v[4]; uint4 qa[4]; unsigned qb[4];
#pragma unroll
            for (int u = 0; u < 4; ++u) v[u] = (unsigned)ebuf[min(k + 2 * u, re - 1)];
#pragma unroll
            for (int u = 0; u < 4; ++u) {
                int s = v[u] & 0x3FFFF;
                qa[u] = hpkA[s];
                qb[u] = hpkB[s];
            }
#pragma unroll
            for (int u = 0; u < 4; ++u) {
                if (k + 2 * u < re) {
                    float2 f01 = up2(qa[u].x), f23 = up2(qa[u].y);
                    float2 f45 = up2(qa[u].z), f67 = up2(qa[u].w);
                    float2 f89 = up2(qb[u]);
                    acc[0] += f01.x; acc[1] += f01.y;
                    acc[2] += f23.x; acc[3] += f23.y;
                    acc[4] += f45.x; acc[5] += f45.y;
                    acc[6] += f67.x; acc[7] += f67.y;
                    acc[8] += f89.x; acc[9] += f89.y;
                }
            }
        }
    } else {
        // ---------- fallback arm: unsorted bucket, LDS atomics (never taken for valid input) ----
        for (int j = t; j < NPB * ACCP; j += blockDim.x) accs[j] = 0.0f;
        __syncthreads();
        int start = nodeoff[b * NPB];
        int end = nodeoff[(b + 1) * NPB];
        for (int e = start + t; e < end; e += blockDim.x) {
            unsigned v = (unsigned)ebuf[e];
            int s = v & 0x3FFFF;
            int ld = v >> 18;
            uint4 qa = hpkA[s]; unsigned qb = hpkB[s];
            float2 f01 = up2(qa.x), f23 = up2(qa.y), f45 = up2(qa.z), f67 = up2(qa.w), f89 = up2(qb);
            float* a = &accs[ld * ACCP];
            atomicAdd(a + 0, f01.x); atomicAdd(a + 1, f01.y);
            atomicAdd(a + 2, f23.x); atomicAdd(a + 3, f23.y);
            atomicAdd(a + 4, f45.x); atomicAdd(a + 5, f45.y);
            atomicAdd(a + 6, f67.x); atomicAdd(a + 7, f67.y);
            atomicAdd(a + 8, f89.x); atomicAdd(a + 9, f89.y);
        }
        __syncthreads();
        if (par == 0) {                 // even lane takes the LDS sum; odd stays 0
#pragma unroll
            for (int f = 0; f < F_HID; ++f) acc[f] = accs[jl * ACCP + f];
        }
    }

    // pair-combine: acc[node] = even-lane acc + odd-lane acc
#pragma unroll
    for (int f = 0; f < F_HID; ++f) acc[f] += __shfl_xor(acc[f], 1);

    if (!valid || par) return;

    uint4 qa = hpkA[i]; unsigned qb = hpkB[i];
    float di = disf[i];
    float2 f01 = up2(qa.x), f23 = up2(qa.y), f45 = up2(qa.z), f67 = up2(qa.w), f89 = up2(qb);
    float hp[F_HID] = {f01.x, f01.y, f23.x, f23.y, f45.x, f45.y, f67.x, f67.y, f89.x, f89.y};

    float hv[F_HID];
#pragma unroll
    for (int f = 0; f < F_HID; ++f) {
        hv[f] = (acc[f] + hp[f]) * di + bgs[f];    // (sum_nbrs h' + h'[i]) * dis[i] + b
        hidden[(long long)i * F_HID + f] = hv[f];
    }
    float4 o;
    float* op = &o.x;
#pragma unroll
    for (int jj = 0; jj < F_OUT; ++jj) {
        float vv = bfs[jj];
#pragma unroll
        for (int f = 0; f < F_HID; ++f) vv += hv[f] * Wfs[f * F_OUT + jj];
        op[jj] = fmaxf(vv, 0.0f);
    }
    o24[i] = o;
}

// ================================================================ FALLBACK (atomic scatter, small ws)
__global__ void fb_init_kernel(const float* __restrict__ x, const float* __restrict__ Wg,
                               float* __restrict__ hpad, float* __restrict__ deg,
                               float* __restrict__ hidden) {
    __shared__ float Ws[F_IN * F_HID];
    for (int t = threadIdx.x; t < F_IN * F_HID; t += blockDim.x) Ws[t] = Wg[t];
    __syncthreads();
    int i = blockIdx.x * blockDim.x + threadIdx.x;
    if (i >= N_NODES) return;
    float acc[F_HID];
#pragma unroll
    for (int f = 0; f < F_HID; ++f) acc[f] = 0.0f;
    const float* xr = x + (long long)i * F_IN;
#pragma unroll
    for (int k = 0; k < F_IN; ++k) {
        float xv = xr[k];
#pragma unroll
        for (int f = 0; f < F_HID; ++f) acc[f] += xv * Ws[k * F_HID + f];
    }
    float* hr = hpad + (long long)i * HPAD;
#pragma unroll
    for (int f = 0; f < F_HID; ++f) hr[f] = acc[f];
    hr[10] = 0.0f; hr[11] = 0.0f;
    deg[i] = 1.0f;
    float* hd = hidden + (long long)i * F_HID;
#pragma unroll
    for (int f = 0; f < F_HID; ++f) hd[f] = 0.0f;
}

__global__ void fb_deg_kernel(const int* __restrict__ ei, const int* __restrict__ mode_p,
                              float* __restrict__ deg) {
    const int mode = *mode_p;
    long long e = (long long)blockIdx.x * blockDim.x + threadIdx.x;
    if (e >= N_EDGES) return;
    int d = load_idx(ei, (long long)N_EDGES + e, mode);
    if ((unsigned)d < (unsigned)N_NODES) atomicAdd(&deg[d], 1.0f);
}

__global__ void fb_scatter_kernel(const int* __restrict__ ei, const int* __restrict__ mode_p,
                                  const float* __restrict__ hpad, const float* __restrict__ deg,
                                  float* __restrict__ hidden) {
    const int mode = *mode_p;
    long long e = (long long)blockIdx.x * blockDim.x + threadIdx.x;
    if (e >= N_EDGES) return;
    int s = load_idx(ei, e, mode);
    int d = load_idx(ei, (long long)N_EDGES + e, mode);
    if ((unsigned)s >= (unsigned)N_NODES || (unsigned)d >= (unsigned)N_NODES) return;
    float norm = rsqrtf(deg[s]) * rsqrtf(deg[d]);
    const float4* h4 = reinterpret_cast<const float4*>(hpad + (long long)s * HPAD);
    float4 a = h4[0]; float4 b = h4[1]; float4 c = h4[2];
    float* o = hidden + (long long)d * F_HID;
    atomicAdd(o + 0, a.x * norm); atomicAdd(o + 1, a.y * norm);
    atomicAdd(o + 2, a.z * norm); atomicAdd(o + 3, a.w * norm);
    atomicAdd(o + 4, b.x * norm); atomicAdd(o + 5, b.y * norm);
    atomicAdd(o + 6, b.z * norm); atomicAdd(o + 7, b.w * norm);
    atomicAdd(o + 8, c.x * norm); atomicAdd(o + 9, c.y * norm);
}

__global__ void fb_finalize_kernel(const float* __restrict__ hpad, const float* __restrict__ deg,
                                   const float* __restrict__ b_gcn, const float* __restrict__ W_fc,
                                   const float* __restrict__ b_fc, float* __restrict__ out) {
    __shared__ float Wf[F_HID * F_OUT];
    __shared__ float bf_s[F_OUT];
    __shared__ float bg_s[F_HID];
    for (int t = threadIdx.x; t < F_HID * F_OUT; t += blockDim.x) Wf[t] = W_fc[t];
    if (threadIdx.x < F_OUT) bf_s[threadIdx.x] = b_fc[threadIdx.x];
    if (threadIdx.x < F_HID) bg_s[threadIdx.x] = b_gcn[threadIdx.x];
    __syncthreads();
    int i = blockIdx.x * blockDim.x + threadIdx.x;
    if (i >= N_NODES) return;
    float* hidden = out;
    float* o2 = out + (long long)N_NODES * F_HID;
    float inv = 1.0f / deg[i];
    const float* hr = hpad + (long long)i * HPAD;
    float* hd = hidden + (long long)i * F_HID;
    float hv[F_HID];
#pragma unroll
    for (int f = 0; f < F_HID; ++f) {
        hv[f] = hd[f] + hr[f] * inv + bg_s[f];
        hd[f] = hv[f];
    }
#pragma unroll
    for (int j = 0; j < F_OUT; ++j) {
        float o = bf_s[j];
#pragma unroll
        for (int f = 0; f < F_HID; ++f) o += hv[f] * Wf[f * F_OUT + j];
        o2[(long long)i * F_OUT + j] = fmaxf(o, 0.0f);
    }
}

// ---------------------------------------------------------------- launch
extern "C" void kernel_launch(void* const* d_in, const int* in_sizes, int n_in,
                              void* d_out, int out_size, void* d_ws, size_t ws_size,
                              hipStream_t stream) {
    const float* x  = (const float*)d_in[0];
    const int*   ei = (const int*)d_in[1];
    const float* Wg = (const float*)d_in[2];
    const float* bg = (const float*)d_in[3];
    const float* Wf = (const float*)d_in[4];
    const float* bf = (const float*)d_in[5];
    float* out = (float*)d_out;

    const int nblk_node = (N_NODES + 255) / 256;     // 782

    // main ws layout (~33.2 MB)
    uint4*    hpkA    = (uint4*)d_ws;                               // N (16B each)
    unsigned* hpkB    = (unsigned*)(hpkA + N_NODES);                // N
    float*    disf    = (float*)(hpkB + N_NODES);                   // N
    int*      bcnt    = (int*)(disf + N_NODES);                     // SCAN_L
    int*      boff    = bcnt + SCAN_L;                              // SCAN_L
    int*      bsum    = boff + SCAN_L;                              // 1024 (NA=1006 used)
    int*      total   = bsum + 1024;                                // 1
    int*      nodeoff = total + 1;                                  // BINS*NPB+1
    int*      flag    = nodeoff + BINS * NPB + 1;                   // BINS
    int*      ebuf    = flag + BINS;                                // N_EDGES
    int*      mode    = ebuf + N_EDGES;                             // 1
    size_t need = (size_t)((char*)(mode + 1) - (char*)d_ws);

    if (ws_size >= need) {
        detect_mode_kernel<<<1, 64, 0, stream>>>(ei, mode);
        p1_count_kernel<<<BLK1, 512, 0, stream>>>(ei, mode, bcnt);
        scanA_kernel<<<NA, 256, 0, stream>>>(bcnt, bsum);
        scanB_kernel<<<1, 1024, 0, stream>>>(bsum, total);
        scanC_kernel<<<NA, 256, 0, stream>>>(bcnt, bsum, boff);
        p3_fill_kernel<<<BLK1, 512, 0, stream>>>(ei, mode, boff, ebuf);
        p5_sort_kernel<<<BINS, 512, 0, stream>>>(ebuf, boff, total, disf, nodeoff, flag);
        init2_kernel<<<nblk_node, 256, 0, stream>>>(x, Wg, disf, hpkA, hpkB);
        p4b_acc_kernel<<<BINS, 512, 0, stream>>>(ebuf, nodeoff, flag, hpkA, hpkB, disf,
                                                 bg, Wf, bf, out);
    } else {
        // fallback: atomic scatter (~10.4 MB)
        float* hpad  = (float*)d_ws;
        float* degf  = hpad + (size_t)N_NODES * HPAD;
        int*   mode2 = (int*)(degf + N_NODES);
        const int nblk_edge = (N_EDGES + 255) / 256;
        detect_mode_kernel<<<1, 64, 0, stream>>>(ei, mode2);
        fb_init_kernel<<<nblk_node, 256, 0, stream>>>(x, Wg, hpad, degf, out);
        fb_deg_kernel<<<nblk_edge, 256, 0, stream>>>(ei, mode2, degf);
        fb_scatter_kernel<<<nblk_edge, 256, 0, stream>>>(ei, mode2, hpad, degf, out);
        fb_finalize_kernel<<<nblk_node, 256, 0, stream>>>(hpad, degf, bg, Wf, bf, out);
    }
}